// Round 1
// baseline (241.410 us; speedup 1.0000x reference)
//
#include <hip/hip_runtime.h>
#include <hip/hip_bf16.h>

// MultiHeadSelfAttention: B=2, S=2048, D=1024, H=16, DK=64
// Pipeline: cast(f32->bf16) -> QKV gemm (bf16 MFMA) -> flash attention -> out-proj gemm (f32 out)

typedef __attribute__((ext_vector_type(4))) float f32x4;
typedef __attribute__((ext_vector_type(8))) short bf16x8;

__device__ __forceinline__ unsigned short f2bf(float f) {
  // round-to-nearest-even f32 -> bf16 (inputs are normal floats; NaN not handled)
  unsigned int u = __float_as_uint(f);
  u += 0x7fffu + ((u >> 16) & 1u);
  return (unsigned short)(u >> 16);
}

__global__ void cast_f32_bf16(const float* __restrict__ src,
                              unsigned short* __restrict__ dst, int n4) {
  int i = blockIdx.x * blockDim.x + threadIdx.x;
  if (i >= n4) return;
  float4 v = ((const float4*)src)[i];
  ushort4 o = make_ushort4(f2bf(v.x), f2bf(v.y), f2bf(v.z), f2bf(v.w));
  ((ushort4*)dst)[i] = o;
}

typedef __attribute__((address_space(1))) const void gas_t;
typedef __attribute__((address_space(3))) void las_t;

__device__ __forceinline__ void gld_lds16(const unsigned short* g, unsigned short* l) {
  __builtin_amdgcn_global_load_lds((gas_t*)g, (las_t*)l, 16, 0, 0);
}

// C = A (M,K) * B(N,K)^T ; A,B bf16 row-major; C row-major (bf16 or f32).
// m97 structure: 128x128 tile, BK=32, 4 waves (2x2 of 64x64), global_load_lds w=16.
template<bool BF16OUT>
__global__ __launch_bounds__(256)
void gemm_bt(const unsigned short* __restrict__ A, const unsigned short* __restrict__ B,
             void* __restrict__ Cv, int M, int N, int K) {
  __shared__ unsigned short As[128 * 32];
  __shared__ unsigned short Bs[128 * 32];
  const int tid = threadIdx.x;
  const int lane = tid & 63;
  const int wid = tid >> 6;
  const int wr = wid >> 1, wc = wid & 1;
  const int lr = lane & 15, lg = lane >> 4;
  const int m0 = blockIdx.x * 128, n0 = blockIdx.y * 128;

  f32x4 acc[4][4] = {};

  const int srow = tid >> 2;          // 0..63
  const int scol = (tid & 3) * 8;     // elem offset 0,8,16,24
  const unsigned short* Ag = A + (size_t)(m0 + srow) * K + scol;
  const unsigned short* Bg = B + (size_t)(n0 + srow) * K + scol;
  unsigned short* Al = &As[tid * 8];  // firstlane -> wave base; HW adds lane*16B
  unsigned short* Bl = &Bs[tid * 8];

  for (int k0 = 0; k0 < K; k0 += 32) {
    gld_lds16(Ag + k0, Al);
    gld_lds16(Ag + k0 + (size_t)64 * K, Al + 2048);
    gld_lds16(Bg + k0, Bl);
    gld_lds16(Bg + k0 + (size_t)64 * K, Bl + 2048);
    asm volatile("s_waitcnt vmcnt(0)" ::: "memory");
    __syncthreads();

    bf16x8 af[4], bfr[4];
#pragma unroll
    for (int i = 0; i < 4; ++i)
      af[i] = *(const bf16x8*)&As[(wr * 64 + i * 16 + lr) * 32 + lg * 8];
#pragma unroll
    for (int j = 0; j < 4; ++j)
      bfr[j] = *(const bf16x8*)&Bs[(wc * 64 + j * 16 + lr) * 32 + lg * 8];
#pragma unroll
    for (int i = 0; i < 4; ++i)
#pragma unroll
      for (int j = 0; j < 4; ++j)
        acc[i][j] = __builtin_amdgcn_mfma_f32_16x16x32_bf16(af[i], bfr[j], acc[i][j], 0, 0, 0);
    __syncthreads();
  }

#pragma unroll
  for (int i = 0; i < 4; ++i) {
    const int row = m0 + wr * 64 + i * 16 + lg * 4;
#pragma unroll
    for (int j = 0; j < 4; ++j) {
      const int col = n0 + wc * 64 + j * 16 + lr;
#pragma unroll
      for (int r = 0; r < 4; ++r) {
        float v = acc[i][j][r];
        size_t idx = (size_t)(row + r) * N + col;
        if (BF16OUT) ((unsigned short*)Cv)[idx] = f2bf(v);
        else         ((float*)Cv)[idx] = v;
      }
    }
  }
}

// Flash attention, causal. QKV: (4096, 3072) bf16 rows = b*2048+s; Q cols [0,1024),
// K cols [1024,2048), V cols [2048,3072), head h at sub-offset h*64.
// Grid (32, 32): blockIdx.y = b*16+h ; block has 2 waves: wave0 -> qt=blockIdx.x,
// wave1 -> qt=63-blockIdx.x (balances causal triangle: 65 KV tiles per wave).
// Per wave: 32 q-rows, KV tiles of 32. No cross-wave sync (per-wave LDS slices).
__global__ __launch_bounds__(128)
void attn_kernel(const unsigned short* __restrict__ QKV, unsigned short* __restrict__ O) {
  const int w = threadIdx.x >> 6;
  const int lane = threadIdx.x & 63;
  const int lr = lane & 15, lg = lane >> 4;
  const int qt = (w == 0) ? (int)blockIdx.x : (63 - (int)blockIdx.x);
  const int bh = blockIdx.y;
  const int b = bh >> 4, h = bh & 15;

  __shared__ unsigned short Plds[2][32 * 32];
  __shared__ unsigned short Vtls[2][64 * 32];
  unsigned short* P  = Plds[w];
  unsigned short* VT = Vtls[w];

  const unsigned short* Qp = QKV + (size_t)(b * 2048 + qt * 32) * 3072 + h * 64;
  const unsigned short* Kp = QKV + (size_t)(b * 2048) * 3072 + 1024 + h * 64;
  const unsigned short* Vp = QKV + (size_t)(b * 2048) * 3072 + 2048 + h * 64;

  bf16x8 qf[2][2];
#pragma unroll
  for (int m = 0; m < 2; ++m)
#pragma unroll
    for (int kk = 0; kk < 2; ++kk)
      qf[m][kk] = *(const bf16x8*)(Qp + (size_t)(m * 16 + lr) * 3072 + kk * 32 + lg * 8);

  f32x4 o[2][4] = {};
  float Mr[2][4], Lr[2][4];
#pragma unroll
  for (int m = 0; m < 2; ++m)
#pragma unroll
    for (int r = 0; r < 4; ++r) { Mr[m][r] = -1e30f; Lr[m][r] = 0.f; }

  const int nt = qt + 1;
  for (int t = 0; t < nt; ++t) {
    const int kv0 = t * 32;

    // --- S = Q K^T (2x2 fragments, K=64 via 2 mfma) ---
    bf16x8 kf[2][2];
#pragma unroll
    for (int n = 0; n < 2; ++n)
#pragma unroll
      for (int kk = 0; kk < 2; ++kk)
        kf[n][kk] = *(const bf16x8*)(Kp + (size_t)(kv0 + n * 16 + lr) * 3072 + kk * 32 + lg * 8);
    f32x4 s[2][2];
#pragma unroll
    for (int m = 0; m < 2; ++m)
#pragma unroll
      for (int n = 0; n < 2; ++n) {
        s[m][n] = (f32x4){0.f, 0.f, 0.f, 0.f};
        s[m][n] = __builtin_amdgcn_mfma_f32_16x16x32_bf16(qf[m][0], kf[n][0], s[m][n], 0, 0, 0);
        s[m][n] = __builtin_amdgcn_mfma_f32_16x16x32_bf16(qf[m][1], kf[n][1], s[m][n], 0, 0, 0);
      }

    // in-wave fence: prior iteration's LDS reads complete before overwrite
    asm volatile("s_waitcnt lgkmcnt(0)" ::: "memory");

    // --- stage V tile transposed into LDS: VT[dk][kv_local] ---
#pragma unroll
    for (int it = 0; it < 4; ++it) {
      int chunk = it * 64 + lane;
      int r = chunk >> 3, cc = (chunk & 7) * 8;
      bf16x8 v = *(const bf16x8*)(Vp + (size_t)(kv0 + r) * 3072 + cc);
#pragma unroll
      for (int j = 0; j < 8; ++j)
        VT[(cc + j) * 32 + r] = (unsigned short)v[j];
    }

    // --- scale + causal mask (only diagonal tile partially masked) ---
    float sv[2][2][4];
#pragma unroll
    for (int m = 0; m < 2; ++m)
#pragma unroll
      for (int n = 0; n < 2; ++n)
#pragma unroll
        for (int r = 0; r < 4; ++r) {
          float x = s[m][n][r] * 0.125f;   // 1/sqrt(64)
          if (t == nt - 1) {
            int col = kv0 + n * 16 + lr;
            int row = qt * 32 + m * 16 + lg * 4 + r;
            if (col > row) x = -1e30f;
          }
          sv[m][n][r] = x;
        }

    // --- online softmax: row stats via 16-lane xor-shuffle reduce ---
#pragma unroll
    for (int m = 0; m < 2; ++m)
#pragma unroll
      for (int r = 0; r < 4; ++r) {
        float mx = fmaxf(sv[m][0][r], sv[m][1][r]);
        mx = fmaxf(mx, __shfl_xor(mx, 1));
        mx = fmaxf(mx, __shfl_xor(mx, 2));
        mx = fmaxf(mx, __shfl_xor(mx, 4));
        mx = fmaxf(mx, __shfl_xor(mx, 8));
        float mnew = fmaxf(Mr[m][r], mx);
        float ef = __expf(Mr[m][r] - mnew);
        Mr[m][r] = mnew;
        float p0 = __expf(sv[m][0][r] - mnew);
        float p1 = __expf(sv[m][1][r] - mnew);
        sv[m][0][r] = p0; sv[m][1][r] = p1;
        float rs = p0 + p1;
        rs += __shfl_xor(rs, 1);
        rs += __shfl_xor(rs, 2);
        rs += __shfl_xor(rs, 4);
        rs += __shfl_xor(rs, 8);
        Lr[m][r] = Lr[m][r] * ef + rs;
#pragma unroll
        for (int n = 0; n < 4; ++n) o[m][n][r] = o[m][n][r] * ef;
      }

    // --- P -> LDS (bf16), then reload as MFMA A-operand ---
#pragma unroll
    for (int m = 0; m < 2; ++m)
#pragma unroll
      for (int n = 0; n < 2; ++n)
#pragma unroll
        for (int r = 0; r < 4; ++r)
          P[(m * 16 + lg * 4 + r) * 32 + n * 16 + lr] = f2bf(sv[m][n][r]);

    asm volatile("s_waitcnt lgkmcnt(0)" ::: "memory");

    bf16x8 pa[2], vf[4];
#pragma unroll
    for (int m = 0; m < 2; ++m)
      pa[m] = *(const bf16x8*)&P[(m * 16 + lr) * 32 + lg * 8];
#pragma unroll
    for (int n = 0; n < 4; ++n)
      vf[n] = *(const bf16x8*)&VT[(n * 16 + lr) * 32 + lg * 8];
#pragma unroll
    for (int m = 0; m < 2; ++m)
#pragma unroll
      for (int n = 0; n < 4; ++n)
        o[m][n] = __builtin_amdgcn_mfma_f32_16x16x32_bf16(pa[m], vf[n], o[m][n], 0, 0, 0);
  }

  // --- epilogue: O / L, write bf16 ---
#pragma unroll
  for (int m = 0; m < 2; ++m)
#pragma unroll
    for (int n = 0; n < 4; ++n)
#pragma unroll
      for (int r = 0; r < 4; ++r) {
        float val = o[m][n][r] / Lr[m][r];
        int row = qt * 32 + m * 16 + lg * 4 + r;
        int col = h * 64 + n * 16 + lr;
        O[(size_t)(b * 2048 + row) * 1024 + col] = f2bf(val);
      }
}

extern "C" void kernel_launch(void* const* d_in, const int* in_sizes, int n_in,
                              void* d_out, int out_size, void* d_ws, size_t ws_size,
                              hipStream_t stream) {
  const float* X  = (const float*)d_in[0];
  const float* Wq = (const float*)d_in[1];
  const float* Wk = (const float*)d_in[2];
  const float* Wv = (const float*)d_in[3];
  const float* Wo = (const float*)d_in[4];
  float* out = (float*)d_out;

  char* ws = (char*)d_ws;
  unsigned short* Xb    = (unsigned short*)(ws);                           // 8 MB
  unsigned short* Wqkvb = (unsigned short*)(ws + (size_t)8  * 1024 * 1024); // 6 MB (Wq,Wk,Wv stacked rows)
  unsigned short* Wob   = (unsigned short*)(ws + (size_t)14 * 1024 * 1024); // 2 MB
  unsigned short* QKV   = (unsigned short*)(ws + (size_t)16 * 1024 * 1024); // 24 MB (4096 x 3072)
  unsigned short* Ob    = (unsigned short*)(ws + (size_t)40 * 1024 * 1024); // 8 MB  (4096 x 1024)

  const int NX4 = (2 * 2048 * 1024) / 4;  // 1048576
  const int NW4 = (1024 * 1024) / 4;      // 262144
  cast_f32_bf16<<<dim3((NX4 + 255) / 256), dim3(256), 0, stream>>>(X, Xb, NX4);
  cast_f32_bf16<<<dim3((NW4 + 255) / 256), dim3(256), 0, stream>>>(Wq, Wqkvb, NW4);
  cast_f32_bf16<<<dim3((NW4 + 255) / 256), dim3(256), 0, stream>>>(Wk, Wqkvb + 1024 * 1024, NW4);
  cast_f32_bf16<<<dim3((NW4 + 255) / 256), dim3(256), 0, stream>>>(Wv, Wqkvb + 2 * 1024 * 1024, NW4);
  cast_f32_bf16<<<dim3((NW4 + 255) / 256), dim3(256), 0, stream>>>(Wo, Wob, NW4);

  // QKV = Xb @ [Wq;Wk;Wv]^T  -> (4096, 3072) bf16
  gemm_bt<true ><<<dim3(32, 24), dim3(256), 0, stream>>>(Xb, Wqkvb, (void*)QKV, 4096, 3072, 1024);
  // causal flash attention -> Ob (4096, 1024) bf16
  attn_kernel<<<dim3(32, 32), dim3(128), 0, stream>>>(QKV, Ob);
  // out = Ob @ Wo^T -> (4096, 1024) f32
  gemm_bt<false><<<dim3(32, 8), dim3(256), 0, stream>>>(Ob, Wob, (void*)out, 4096, 1024, 1024);
}

// Round 2
// 210.782 us; speedup vs baseline: 1.1453x; 1.1453x over previous
//
#include <hip/hip_runtime.h>
#include <hip/hip_bf16.h>

// MultiHeadSelfAttention: B=2, S=2048, D=1024, H=16, DK=64
// cast(f32->bf16) -> QKV gemm -> transpose V -> flash attention -> out-proj gemm

typedef __attribute__((ext_vector_type(4))) float f32x4;
typedef __attribute__((ext_vector_type(8))) short bf16x8;

__device__ __forceinline__ unsigned short f2bf(float f) {
  unsigned int u = __float_as_uint(f);
  u += 0x7fffu + ((u >> 16) & 1u);
  return (unsigned short)(u >> 16);
}

__global__ void cast_f32_bf16(const float* __restrict__ src,
                              unsigned short* __restrict__ dst, int n4) {
  int i = blockIdx.x * blockDim.x + threadIdx.x;
  if (i >= n4) return;
  float4 v = ((const float4*)src)[i];
  ushort4 o = make_ushort4(f2bf(v.x), f2bf(v.y), f2bf(v.z), f2bf(v.w));
  ((ushort4*)dst)[i] = o;
}

typedef __attribute__((address_space(1))) const void gas_t;
typedef __attribute__((address_space(3))) void las_t;

__device__ __forceinline__ void gld_lds16(const unsigned short* g, unsigned short* l) {
  __builtin_amdgcn_global_load_lds((gas_t*)g, (las_t*)l, 16, 0, 0);
}

// C = A (M,K) * B(N,K)^T ; bf16 in, bf16 or f32 out. m97 structure.
template<bool BF16OUT>
__global__ __launch_bounds__(256)
void gemm_bt(const unsigned short* __restrict__ A, const unsigned short* __restrict__ B,
             void* __restrict__ Cv, int M, int N, int K) {
  __shared__ unsigned short As[128 * 32];
  __shared__ unsigned short Bs[128 * 32];
  const int tid = threadIdx.x;
  const int lane = tid & 63;
  const int wid = tid >> 6;
  const int wr = wid >> 1, wc = wid & 1;
  const int lr = lane & 15, lg = lane >> 4;
  const int m0 = blockIdx.x * 128, n0 = blockIdx.y * 128;

  f32x4 acc[4][4] = {};

  const int srow = tid >> 2;
  const int scol = (tid & 3) * 8;
  const unsigned short* Ag = A + (size_t)(m0 + srow) * K + scol;
  const unsigned short* Bg = B + (size_t)(n0 + srow) * K + scol;
  unsigned short* Al = &As[tid * 8];
  unsigned short* Bl = &Bs[tid * 8];

  for (int k0 = 0; k0 < K; k0 += 32) {
    gld_lds16(Ag + k0, Al);
    gld_lds16(Ag + k0 + (size_t)64 * K, Al + 2048);
    gld_lds16(Bg + k0, Bl);
    gld_lds16(Bg + k0 + (size_t)64 * K, Bl + 2048);
    asm volatile("s_waitcnt vmcnt(0)" ::: "memory");
    __syncthreads();

    bf16x8 af[4], bfr[4];
#pragma unroll
    for (int i = 0; i < 4; ++i)
      af[i] = *(const bf16x8*)&As[(wr * 64 + i * 16 + lr) * 32 + lg * 8];
#pragma unroll
    for (int j = 0; j < 4; ++j)
      bfr[j] = *(const bf16x8*)&Bs[(wc * 64 + j * 16 + lr) * 32 + lg * 8];
#pragma unroll
    for (int i = 0; i < 4; ++i)
#pragma unroll
      for (int j = 0; j < 4; ++j)
        acc[i][j] = __builtin_amdgcn_mfma_f32_16x16x32_bf16(af[i], bfr[j], acc[i][j], 0, 0, 0);
    __syncthreads();
  }

#pragma unroll
  for (int i = 0; i < 4; ++i) {
    const int row = m0 + wr * 64 + i * 16 + lg * 4;
#pragma unroll
    for (int j = 0; j < 4; ++j) {
      const int col = n0 + wc * 64 + j * 16 + lr;
#pragma unroll
      for (int r = 0; r < 4; ++r) {
        float v = acc[i][j][r];
        size_t idx = (size_t)(row + r) * N + col;
        if (BF16OUT) ((unsigned short*)Cv)[idx] = f2bf(v);
        else         ((float*)Cv)[idx] = v;
      }
    }
  }
}

// VT[(bh*64 + d)*2048 + s] = QKV[(b*2048+s)*3072 + 2048 + h*64 + d]
// 64x64 tile per block; double-XOR chunk swizzle so both LDS write (row-wise)
// and LDS read (column-wise) are bank-conflict-free.
__global__ __launch_bounds__(256)
void transpose_v(const unsigned short* __restrict__ QKV, unsigned short* __restrict__ VT) {
  __shared__ __align__(16) unsigned short t[64 * 64];
  const int tid = threadIdx.x;
  const int bh = blockIdx.y, b = bh >> 4, h = bh & 15;
  const int s0 = blockIdx.x * 64;
#pragma unroll
  for (int it = 0; it < 2; ++it) {
    int idx = it * 256 + tid;
    int r = idx >> 3, c8 = (idx & 7) * 8;
    bf16x8 v = *(const bf16x8*)(QKV + (size_t)(b * 2048 + s0 + r) * 3072 + 2048 + h * 64 + c8);
    int sw = ((r & 7) ^ ((r >> 3) & 7)) * 8;
    *(bf16x8*)&t[r * 64 + (c8 ^ sw)] = v;
  }
  __syncthreads();
#pragma unroll
  for (int it = 0; it < 2; ++it) {
    int idx = it * 256 + tid;
    int d = idx >> 3, s8 = (idx & 7) * 8;
    unsigned short tmp[8];
#pragma unroll
    for (int j = 0; j < 8; ++j) {
      int row = s8 + j;
      int sw = ((row & 7) ^ ((row >> 3) & 7)) * 8;
      tmp[j] = t[row * 64 + ((d & ~7) ^ sw) + (d & 7)];
    }
    *(bf16x8*)(VT + (size_t)(bh * 64 + d) * 2048 + s0 + s8) = *(bf16x8*)tmp;
  }
}

// Flash attention, causal. Each wave handles q-tile pair (p, 127-p), 16 rows each,
// KV tiles of 32 -> exactly 65 kv-tiles per wave (balanced). V^T read from global.
__global__ __launch_bounds__(128)
void attn2(const unsigned short* __restrict__ QKV, const unsigned short* __restrict__ VT,
           unsigned short* __restrict__ O) {
  const int w = threadIdx.x >> 6;
  const int lane = threadIdx.x & 63;
  const int lr = lane & 15, lg = lane >> 4;
  const int bh = blockIdx.y, b = bh >> 4, h = bh & 15;
  const int p0 = blockIdx.x * 2 + w;

  __shared__ __align__(16) unsigned short Pl[2][16 * 40];  // padded stride 40
  unsigned short* P = Pl[w];

  const unsigned short* Qb = QKV + (size_t)b * 2048 * 3072 + h * 64;
  const unsigned short* Kb = QKV + (size_t)b * 2048 * 3072 + 1024 + h * 64;
  const unsigned short* Vt = VT + (size_t)bh * 64 * 2048;

  const float sc = 0.125f * 1.44269504088896f;  // 1/sqrt(64) * log2(e)

  for (int ph = 0; ph < 2; ++ph) {
    const int qp = (ph == 0) ? p0 : (127 - p0);
    const int nt = qp / 2 + 1;

    bf16x8 qf[2];
    qf[0] = *(const bf16x8*)(Qb + (size_t)(qp * 16 + lr) * 3072 + lg * 8);
    qf[1] = *(const bf16x8*)(Qb + (size_t)(qp * 16 + lr) * 3072 + 32 + lg * 8);

    f32x4 o[4] = {};
    float Mr[4], Lr[4];
#pragma unroll
    for (int r = 0; r < 4; ++r) { Mr[r] = -1e30f; Lr[r] = 0.f; }

    bf16x8 kc[2][2], kn[2][2];
#pragma unroll
    for (int n = 0; n < 2; ++n) {
      kc[n][0] = *(const bf16x8*)(Kb + (size_t)(n * 16 + lr) * 3072 + lg * 8);
      kc[n][1] = *(const bf16x8*)(Kb + (size_t)(n * 16 + lr) * 3072 + 32 + lg * 8);
    }

    for (int t = 0; t < nt; ++t) {
      // --- S = Q K^T ---
      f32x4 s[2];
#pragma unroll
      for (int n = 0; n < 2; ++n) {
        s[n] = (f32x4){0.f, 0.f, 0.f, 0.f};
        s[n] = __builtin_amdgcn_mfma_f32_16x16x32_bf16(qf[0], kc[n][0], s[n], 0, 0, 0);
        s[n] = __builtin_amdgcn_mfma_f32_16x16x32_bf16(qf[1], kc[n][1], s[n], 0, 0, 0);
      }

      // prefetch next K tile (register dbuf) + this tile's V^T frags
      if (t + 1 < nt) {
#pragma unroll
        for (int n = 0; n < 2; ++n) {
          kn[n][0] = *(const bf16x8*)(Kb + (size_t)((t + 1) * 32 + n * 16 + lr) * 3072 + lg * 8);
          kn[n][1] = *(const bf16x8*)(Kb + (size_t)((t + 1) * 32 + n * 16 + lr) * 3072 + 32 + lg * 8);
        }
      }
      bf16x8 vf[4];
#pragma unroll
      for (int n = 0; n < 4; ++n)
        vf[n] = *(const bf16x8*)(Vt + (size_t)(n * 16 + lr) * 2048 + t * 32 + lg * 8);

      // --- scale (+ causal mask on last tile), log2 domain ---
      float sv[2][4];
      const bool last = (t == nt - 1);
#pragma unroll
      for (int n = 0; n < 2; ++n)
#pragma unroll
        for (int r = 0; r < 4; ++r)
          sv[n][r] = s[n][r] * sc;
      if (last) {
#pragma unroll
        for (int n = 0; n < 2; ++n)
#pragma unroll
          for (int r = 0; r < 4; ++r) {
            int col = t * 32 + n * 16 + lr;
            int row = qp * 16 + lg * 4 + r;
            if (col > row) sv[n][r] = -3.0e38f;
          }
      }

      // --- online softmax: max via 16-lane shuffle; L kept lane-partial ---
#pragma unroll
      for (int r = 0; r < 4; ++r) {
        float mx = fmaxf(sv[0][r], sv[1][r]);
        mx = fmaxf(mx, __shfl_xor(mx, 1));
        mx = fmaxf(mx, __shfl_xor(mx, 2));
        mx = fmaxf(mx, __shfl_xor(mx, 4));
        mx = fmaxf(mx, __shfl_xor(mx, 8));
        float mnew = fmaxf(Mr[r], mx);
        float ef = exp2f(Mr[r] - mnew);
        Mr[r] = mnew;
        float p0e = exp2f(sv[0][r] - mnew);
        float p1e = exp2f(sv[1][r] - mnew);
        sv[0][r] = p0e; sv[1][r] = p1e;
        Lr[r] = Lr[r] * ef + p0e + p1e;
#pragma unroll
        for (int n = 0; n < 4; ++n) o[n][r] *= ef;
      }

      // --- P -> LDS (padded), reload as A-frag ---
#pragma unroll
      for (int n = 0; n < 2; ++n)
#pragma unroll
        for (int r = 0; r < 4; ++r)
          P[(lg * 4 + r) * 40 + n * 16 + lr] = f2bf(sv[n][r]);
      asm volatile("s_waitcnt lgkmcnt(0)" ::: "memory");
      bf16x8 pa = *(const bf16x8*)&P[lr * 40 + lg * 8];

      // --- O += P V ---
#pragma unroll
      for (int n = 0; n < 4; ++n)
        o[n] = __builtin_amdgcn_mfma_f32_16x16x32_bf16(pa, vf[n], o[n], 0, 0, 0);

      if (t + 1 < nt) {
#pragma unroll
        for (int n = 0; n < 2; ++n) {
          kc[n][0] = kn[n][0];
          kc[n][1] = kn[n][1];
        }
      }
    }

    // --- epilogue: reduce L across the 16 row-lanes, write O/L ---
#pragma unroll
    for (int r = 0; r < 4; ++r) {
      float L = Lr[r];
      L += __shfl_xor(L, 1);
      L += __shfl_xor(L, 2);
      L += __shfl_xor(L, 4);
      L += __shfl_xor(L, 8);
      float inv = 1.0f / L;
      int row = qp * 16 + lg * 4 + r;
#pragma unroll
      for (int n = 0; n < 4; ++n) {
        float val = o[n][r] * inv;
        O[(size_t)(b * 2048 + row) * 1024 + h * 64 + n * 16 + lr] = f2bf(val);
      }
    }
  }
}

extern "C" void kernel_launch(void* const* d_in, const int* in_sizes, int n_in,
                              void* d_out, int out_size, void* d_ws, size_t ws_size,
                              hipStream_t stream) {
  const float* X  = (const float*)d_in[0];
  const float* Wq = (const float*)d_in[1];
  const float* Wk = (const float*)d_in[2];
  const float* Wv = (const float*)d_in[3];
  const float* Wo = (const float*)d_in[4];
  float* out = (float*)d_out;

  char* ws = (char*)d_ws;
  unsigned short* Xb    = (unsigned short*)(ws);                            // 8 MB (dead after QKV gemm)
  unsigned short* VTg   = (unsigned short*)(ws);                            // 8 MB (reuses Xb region)
  unsigned short* Wqkvb = (unsigned short*)(ws + (size_t)8  * 1024 * 1024); // 6 MB
  unsigned short* Wob   = (unsigned short*)(ws + (size_t)14 * 1024 * 1024); // 2 MB
  unsigned short* QKV   = (unsigned short*)(ws + (size_t)16 * 1024 * 1024); // 24 MB
  unsigned short* Ob    = (unsigned short*)(ws + (size_t)40 * 1024 * 1024); // 8 MB

  const int NX4 = (2 * 2048 * 1024) / 4;
  const int NW4 = (1024 * 1024) / 4;
  cast_f32_bf16<<<dim3((NX4 + 255) / 256), dim3(256), 0, stream>>>(X, Xb, NX4);
  cast_f32_bf16<<<dim3((NW4 + 255) / 256), dim3(256), 0, stream>>>(Wq, Wqkvb, NW4);
  cast_f32_bf16<<<dim3((NW4 + 255) / 256), dim3(256), 0, stream>>>(Wk, Wqkvb + 1024 * 1024, NW4);
  cast_f32_bf16<<<dim3((NW4 + 255) / 256), dim3(256), 0, stream>>>(Wv, Wqkvb + 2 * 1024 * 1024, NW4);
  cast_f32_bf16<<<dim3((NW4 + 255) / 256), dim3(256), 0, stream>>>(Wo, Wob, NW4);

  gemm_bt<true ><<<dim3(32, 24), dim3(256), 0, stream>>>(Xb, Wqkvb, (void*)QKV, 4096, 3072, 1024);
  transpose_v<<<dim3(32, 32), dim3(256), 0, stream>>>(QKV, VTg);
  attn2<<<dim3(32, 32), dim3(128), 0, stream>>>(QKV, VTg, Ob);
  gemm_bt<false><<<dim3(32, 8), dim3(256), 0, stream>>>(Ob, Wob, (void*)out, 4096, 1024, 1024);
}

// Round 3
// 206.072 us; speedup vs baseline: 1.1715x; 1.0229x over previous
//
#include <hip/hip_runtime.h>
#include <hip/hip_bf16.h>

// MultiHeadSelfAttention: B=2, S=2048, D=1024, H=16, DK=64
// cast(f32->bf16) -> QKV gemm -> transpose V -> flash attention (XCD-local) -> out-proj gemm

typedef __attribute__((ext_vector_type(4))) float f32x4;
typedef __attribute__((ext_vector_type(8))) short bf16x8;

__device__ __forceinline__ unsigned short f2bf(float f) {
  unsigned int u = __float_as_uint(f);
  u += 0x7fffu + ((u >> 16) & 1u);
  return (unsigned short)(u >> 16);
}

__global__ void cast_f32_bf16(const float* __restrict__ src,
                              unsigned short* __restrict__ dst, int n4) {
  int i = blockIdx.x * blockDim.x + threadIdx.x;
  if (i >= n4) return;
  float4 v = ((const float4*)src)[i];
  ushort4 o = make_ushort4(f2bf(v.x), f2bf(v.y), f2bf(v.z), f2bf(v.w));
  ((ushort4*)dst)[i] = o;
}

typedef __attribute__((address_space(1))) const void gas_t;
typedef __attribute__((address_space(3))) void las_t;

__device__ __forceinline__ void gld_lds16(const unsigned short* g, unsigned short* l) {
  __builtin_amdgcn_global_load_lds((gas_t*)g, (las_t*)l, 16, 0, 0);
}

// C = A (M,K) * B(N,K)^T ; bf16 in, bf16 or f32 out. m97 structure.
template<bool BF16OUT>
__global__ __launch_bounds__(256)
void gemm_bt(const unsigned short* __restrict__ A, const unsigned short* __restrict__ B,
             void* __restrict__ Cv, int M, int N, int K) {
  __shared__ unsigned short As[128 * 32];
  __shared__ unsigned short Bs[128 * 32];
  const int tid = threadIdx.x;
  const int lane = tid & 63;
  const int wid = tid >> 6;
  const int wr = wid >> 1, wc = wid & 1;
  const int lr = lane & 15, lg = lane >> 4;
  const int m0 = blockIdx.x * 128, n0 = blockIdx.y * 128;

  f32x4 acc[4][4] = {};

  const int srow = tid >> 2;
  const int scol = (tid & 3) * 8;
  const unsigned short* Ag = A + (size_t)(m0 + srow) * K + scol;
  const unsigned short* Bg = B + (size_t)(n0 + srow) * K + scol;
  unsigned short* Al = &As[tid * 8];
  unsigned short* Bl = &Bs[tid * 8];

  for (int k0 = 0; k0 < K; k0 += 32) {
    gld_lds16(Ag + k0, Al);
    gld_lds16(Ag + k0 + (size_t)64 * K, Al + 2048);
    gld_lds16(Bg + k0, Bl);
    gld_lds16(Bg + k0 + (size_t)64 * K, Bl + 2048);
    asm volatile("s_waitcnt vmcnt(0)" ::: "memory");
    __syncthreads();

    bf16x8 af[4], bfr[4];
#pragma unroll
    for (int i = 0; i < 4; ++i)
      af[i] = *(const bf16x8*)&As[(wr * 64 + i * 16 + lr) * 32 + lg * 8];
#pragma unroll
    for (int j = 0; j < 4; ++j)
      bfr[j] = *(const bf16x8*)&Bs[(wc * 64 + j * 16 + lr) * 32 + lg * 8];
#pragma unroll
    for (int i = 0; i < 4; ++i)
#pragma unroll
      for (int j = 0; j < 4; ++j)
        acc[i][j] = __builtin_amdgcn_mfma_f32_16x16x32_bf16(af[i], bfr[j], acc[i][j], 0, 0, 0);
    __syncthreads();
  }

#pragma unroll
  for (int i = 0; i < 4; ++i) {
    const int row = m0 + wr * 64 + i * 16 + lg * 4;
#pragma unroll
    for (int j = 0; j < 4; ++j) {
      const int col = n0 + wc * 64 + j * 16 + lr;
#pragma unroll
      for (int r = 0; r < 4; ++r) {
        float v = acc[i][j][r];
        size_t idx = (size_t)(row + r) * N + col;
        if (BF16OUT) ((unsigned short*)Cv)[idx] = f2bf(v);
        else         ((float*)Cv)[idx] = v;
      }
    }
  }
}

// VT[(bh*64 + d)*2048 + s] = QKV[(b*2048+s)*3072 + 2048 + h*64 + d]
__global__ __launch_bounds__(256)
void transpose_v(const unsigned short* __restrict__ QKV, unsigned short* __restrict__ VT) {
  __shared__ __align__(16) unsigned short t[64 * 64];
  const int tid = threadIdx.x;
  const int bh = blockIdx.y, b = bh >> 4, h = bh & 15;
  const int s0 = blockIdx.x * 64;
#pragma unroll
  for (int it = 0; it < 2; ++it) {
    int idx = it * 256 + tid;
    int r = idx >> 3, c8 = (idx & 7) * 8;
    bf16x8 v = *(const bf16x8*)(QKV + (size_t)(b * 2048 + s0 + r) * 3072 + 2048 + h * 64 + c8);
    int sw = ((r & 7) ^ ((r >> 3) & 7)) * 8;
    *(bf16x8*)&t[r * 64 + (c8 ^ sw)] = v;
  }
  __syncthreads();
#pragma unroll
  for (int it = 0; it < 2; ++it) {
    int idx = it * 256 + tid;
    int d = idx >> 3, s8 = (idx & 7) * 8;
    unsigned short tmp[8];
#pragma unroll
    for (int j = 0; j < 8; ++j) {
      int row = s8 + j;
      int sw = ((row & 7) ^ ((row >> 3) & 7)) * 8;
      tmp[j] = t[row * 64 + ((d & ~7) ^ sw) + (d & 7)];
    }
    *(bf16x8*)(VT + (size_t)(bh * 64 + d) * 2048 + s0 + s8) = *(bf16x8*)tmp;
  }
}

// Flash attention, causal, KVBLK=64. 1-D grid of 1024 blocks, XCD-partitioned:
// xcd = lb&7 (HW round-robin), each XCD owns 4 bh -> KV working set 2MB fits L2.
// Wave handles q-tile pair (p0, 127-p0), 16 rows each -> 33 kv-tiles, balanced.
// K and V register-double-buffered one tile ahead; defer-max online softmax.
__global__ __launch_bounds__(128)
void attn3(const unsigned short* __restrict__ QKV, const unsigned short* __restrict__ VT,
           unsigned short* __restrict__ O) {
  const int w = threadIdx.x >> 6;
  const int lane = threadIdx.x & 63;
  const int lr = lane & 15, lg = lane >> 4;
  const int lb = blockIdx.x;
  const int xcd = lb & 7;
  const int j = lb >> 3;                // 0..127 within xcd
  const int bh = xcd * 4 + (j >> 5);    // 4 bh per XCD
  const int qpair = j & 31;             // 0..31
  const int b = bh >> 4, h = bh & 15;
  const int p0 = qpair * 2 + w;         // 0..63

  __shared__ __align__(16) unsigned short Pl[2][16 * 72];  // padded stride 72
  unsigned short* P = Pl[w];

  const unsigned short* Qb = QKV + (size_t)b * 2048 * 3072 + h * 64;
  const unsigned short* Kb = QKV + (size_t)b * 2048 * 3072 + 1024 + h * 64;
  const unsigned short* Vt = VT + (size_t)bh * 64 * 2048;

  const float sc = 0.125f * 1.44269504088896f;  // 1/sqrt(64) * log2(e)

  for (int ph = 0; ph < 2; ++ph) {
    const int qp = (ph == 0) ? p0 : (127 - p0);
    const int nt = qp / 4 + 1;   // KV tiles of 64

    bf16x8 qf[2];
    qf[0] = *(const bf16x8*)(Qb + (size_t)(qp * 16 + lr) * 3072 + lg * 8);
    qf[1] = *(const bf16x8*)(Qb + (size_t)(qp * 16 + lr) * 3072 + 32 + lg * 8);

    f32x4 o[4] = {};
    float Mr[4], Lr[4];
#pragma unroll
    for (int r = 0; r < 4; ++r) { Mr[r] = -1e30f; Lr[r] = 0.f; }

    bf16x8 kc[4][2], kn[4][2], vc[4][2], vn[4][2];
#pragma unroll
    for (int n = 0; n < 4; ++n)
#pragma unroll
      for (int c = 0; c < 2; ++c) {
        kc[n][c] = *(const bf16x8*)(Kb + (size_t)(n * 16 + lr) * 3072 + c * 32 + lg * 8);
        vc[n][c] = *(const bf16x8*)(Vt + (size_t)(n * 16 + lr) * 2048 + c * 32 + lg * 8);
      }

    for (int t = 0; t < nt; ++t) {
      // --- S = Q K^T ---
      f32x4 s[4];
#pragma unroll
      for (int n = 0; n < 4; ++n) {
        s[n] = (f32x4){0.f, 0.f, 0.f, 0.f};
        s[n] = __builtin_amdgcn_mfma_f32_16x16x32_bf16(qf[0], kc[n][0], s[n], 0, 0, 0);
        s[n] = __builtin_amdgcn_mfma_f32_16x16x32_bf16(qf[1], kc[n][1], s[n], 0, 0, 0);
      }

      // --- prefetch next tile's K and V (latency hides under softmax+PV) ---
      if (t + 1 < nt) {
#pragma unroll
        for (int n = 0; n < 4; ++n)
#pragma unroll
          for (int c = 0; c < 2; ++c) {
            kn[n][c] = *(const bf16x8*)(Kb + (size_t)((t + 1) * 64 + n * 16 + lr) * 3072 + c * 32 + lg * 8);
            vn[n][c] = *(const bf16x8*)(Vt + (size_t)(n * 16 + lr) * 2048 + (t + 1) * 64 + c * 32 + lg * 8);
          }
      }

      // --- scale (+ causal mask on diagonal tile), log2 domain ---
      float sv[4][4];
#pragma unroll
      for (int n = 0; n < 4; ++n)
#pragma unroll
        for (int r = 0; r < 4; ++r)
          sv[n][r] = s[n][r] * sc;
      if (t == nt - 1) {
#pragma unroll
        for (int n = 0; n < 4; ++n)
#pragma unroll
          for (int r = 0; r < 4; ++r) {
            int col = t * 64 + n * 16 + lr;
            int row = qp * 16 + lg * 4 + r;
            if (col > row) sv[n][r] = -3.0e38f;
          }
      }

      // --- online softmax with defer-max (THR=8 in log2 domain) ---
      float mx[4];
#pragma unroll
      for (int r = 0; r < 4; ++r) {
        float m0 = fmaxf(fmaxf(sv[0][r], sv[1][r]), fmaxf(sv[2][r], sv[3][r]));
        m0 = fmaxf(m0, __shfl_xor(m0, 1));
        m0 = fmaxf(m0, __shfl_xor(m0, 2));
        m0 = fmaxf(m0, __shfl_xor(m0, 4));
        m0 = fmaxf(m0, __shfl_xor(m0, 8));
        mx[r] = m0;
      }
      bool changed = false;
      float mnew[4];
#pragma unroll
      for (int r = 0; r < 4; ++r) {
        mnew[r] = (mx[r] > Mr[r] + 8.0f) ? mx[r] : Mr[r];
        changed = changed || (mnew[r] != Mr[r]);
      }
      if (__any(changed)) {
#pragma unroll
        for (int r = 0; r < 4; ++r) {
          float ef = exp2f(Mr[r] - mnew[r]);
          Mr[r] = mnew[r];
          Lr[r] *= ef;
#pragma unroll
          for (int n = 0; n < 4; ++n) o[n][r] *= ef;
        }
      }
#pragma unroll
      for (int r = 0; r < 4; ++r) {
        float rs = 0.f;
#pragma unroll
        for (int n = 0; n < 4; ++n) {
          float p = exp2f(sv[n][r] - Mr[r]);
          sv[n][r] = p;
          rs += p;
        }
        Lr[r] += rs;   // lane-partial; reduced in epilogue
      }

      // --- P -> LDS (padded), reload as A-frags ---
#pragma unroll
      for (int n = 0; n < 4; ++n)
#pragma unroll
        for (int r = 0; r < 4; ++r)
          P[(lg * 4 + r) * 72 + n * 16 + lr] = f2bf(sv[n][r]);
      asm volatile("s_waitcnt lgkmcnt(0)" ::: "memory");
      bf16x8 pa[2];
      pa[0] = *(const bf16x8*)&P[lr * 72 + lg * 8];
      pa[1] = *(const bf16x8*)&P[lr * 72 + 32 + lg * 8];

      // --- O += P V ---
#pragma unroll
      for (int n = 0; n < 4; ++n) {
        o[n] = __builtin_amdgcn_mfma_f32_16x16x32_bf16(pa[0], vc[n][0], o[n], 0, 0, 0);
        o[n] = __builtin_amdgcn_mfma_f32_16x16x32_bf16(pa[1], vc[n][1], o[n], 0, 0, 0);
      }

      if (t + 1 < nt) {
#pragma unroll
        for (int n = 0; n < 4; ++n)
#pragma unroll
          for (int c = 0; c < 2; ++c) {
            kc[n][c] = kn[n][c];
            vc[n][c] = vn[n][c];
          }
      }
    }

    // --- epilogue: reduce L across 16 row-lanes, write O/L ---
#pragma unroll
    for (int r = 0; r < 4; ++r) {
      float L = Lr[r];
      L += __shfl_xor(L, 1);
      L += __shfl_xor(L, 2);
      L += __shfl_xor(L, 4);
      L += __shfl_xor(L, 8);
      float inv = 1.0f / L;
      int row = qp * 16 + lg * 4 + r;
#pragma unroll
      for (int n = 0; n < 4; ++n) {
        float val = o[n][r] * inv;
        O[(size_t)(b * 2048 + row) * 1024 + h * 64 + n * 16 + lr] = f2bf(val);
      }
    }
  }
}

extern "C" void kernel_launch(void* const* d_in, const int* in_sizes, int n_in,
                              void* d_out, int out_size, void* d_ws, size_t ws_size,
                              hipStream_t stream) {
  const float* X  = (const float*)d_in[0];
  const float* Wq = (const float*)d_in[1];
  const float* Wk = (const float*)d_in[2];
  const float* Wv = (const float*)d_in[3];
  const float* Wo = (const float*)d_in[4];
  float* out = (float*)d_out;

  char* ws = (char*)d_ws;
  unsigned short* Xb    = (unsigned short*)(ws);                            // 8 MB (dead after QKV gemm)
  unsigned short* VTg   = (unsigned short*)(ws);                            // 8 MB (reuses Xb region)
  unsigned short* Wqkvb = (unsigned short*)(ws + (size_t)8  * 1024 * 1024); // 6 MB
  unsigned short* Wob   = (unsigned short*)(ws + (size_t)14 * 1024 * 1024); // 2 MB
  unsigned short* QKV   = (unsigned short*)(ws + (size_t)16 * 1024 * 1024); // 24 MB
  unsigned short* Ob    = (unsigned short*)(ws + (size_t)40 * 1024 * 1024); // 8 MB

  const int NX4 = (2 * 2048 * 1024) / 4;
  const int NW4 = (1024 * 1024) / 4;
  cast_f32_bf16<<<dim3((NX4 + 255) / 256), dim3(256), 0, stream>>>(X, Xb, NX4);
  cast_f32_bf16<<<dim3((NW4 + 255) / 256), dim3(256), 0, stream>>>(Wq, Wqkvb, NW4);
  cast_f32_bf16<<<dim3((NW4 + 255) / 256), dim3(256), 0, stream>>>(Wk, Wqkvb + 1024 * 1024, NW4);
  cast_f32_bf16<<<dim3((NW4 + 255) / 256), dim3(256), 0, stream>>>(Wv, Wqkvb + 2 * 1024 * 1024, NW4);
  cast_f32_bf16<<<dim3((NW4 + 255) / 256), dim3(256), 0, stream>>>(Wo, Wob, NW4);

  gemm_bt<true ><<<dim3(32, 24), dim3(256), 0, stream>>>(Xb, Wqkvb, (void*)QKV, 4096, 3072, 1024);
  transpose_v<<<dim3(32, 32), dim3(256), 0, stream>>>(QKV, VTg);
  attn3<<<dim3(1024), dim3(128), 0, stream>>>(QKV, VTg, Ob);
  gemm_bt<false><<<dim3(32, 8), dim3(256), 0, stream>>>(Ob, Wob, (void*)out, 4096, 1024, 1024);
}